// Round 1
// baseline (661.572 us; speedup 1.0000x reference)
//
#include <hip/hip_runtime.h>
#include <hip/hip_bf16.h>

#define NN 10000
#define KK 32
#define HH 128
#define TFH 32      // T_F/2
#define RFE 32
#define OUTF 64
#define START_T 0.25f
#define END_T 0.75f
#define ATTN_NORM 0.25f
#define T_NORM 0.17677669529663687f   // sqrt(1/32)
#define LN_EPS 1e-5f
#define NPB 16

__device__ __forceinline__ float blocksum128(float v, float* red){
  #pragma unroll
  for (int off=32; off; off>>=1) v += __shfl_down(v, off, 64);
  __syncthreads();
  if ((threadIdx.x & 63)==0) red[threadIdx.x>>6] = v;
  __syncthreads();
  return red[0]+red[1];
}

// h = relu(x @ Wp + bp)
__global__ __launch_bounds__(128) void k_proj(const float* __restrict__ X, const float* __restrict__ W,
                                              const float* __restrict__ b, float* __restrict__ Y){
  __shared__ float xs[NPB][HH];
  const int n0 = blockIdx.x*NPB, j = threadIdx.x;
  #pragma unroll
  for (int r=0;r<NPB;r++) xs[r][j] = X[(size_t)(n0+r)*HH + j];
  __syncthreads();
  float acc[NPB];
  #pragma unroll
  for (int r=0;r<NPB;r++) acc[r]=0.f;
  for (int i=0;i<HH;i++){
    const float w = W[i*HH + j];
    #pragma unroll
    for (int r=0;r<NPB;r++) acc[r] = fmaf(xs[r][i], w, acc[r]);
  }
  const float bj = b[j];
  #pragma unroll
  for (int r=0;r<NPB;r++) Y[(size_t)(n0+r)*HH + j] = fmaxf(acc[r]+bj, 0.f);
}

// per node: tmax (masked max of times, floor START_T) and t_qq = (t2v(tmax-START_T) @ Wtime)[:, H:2H]
__global__ __launch_bounds__(128) void k_prep_node(const float* __restrict__ times, const float* __restrict__ Wt,
                                                   const float* __restrict__ bt, const float* __restrict__ Wtime,
                                                   float* __restrict__ tqq, float* __restrict__ tmaxb){
  __shared__ float temb[2*TFH];
  __shared__ float tm_sh;
  const int n = blockIdx.x, j = threadIdx.x;
  if (j < KK){
    float t = times[n*KK + j];
    bool valid = (t >= START_T) && (t < END_T);
    float val = valid ? t : START_T;
    #pragma unroll
    for (int off=16; off; off>>=1) val = fmaxf(val, __shfl_xor(val, off, 32));
    if (j==0){ tm_sh = val; tmaxb[n] = val; }
  }
  __syncthreads();
  if (j < TFH){
    float hh = fmaf(tm_sh - START_T, Wt[j], bt[j]);
    temb[2*j]   = __sinf(hh)*T_NORM;
    temb[2*j+1] = __cosf(hh)*T_NORM;
  }
  __syncthreads();
  float acc = 0.f;
  #pragma unroll
  for (int f=0; f<2*TFH; f++) acc = fmaf(temb[f], Wtime[f*384 + HH + j], acc);
  tqq[n*HH + j] = acc;
}

// once: kadd/vadd for all (n,k) pairs, bf16. One node (32 pairs) per block.
__global__ __launch_bounds__(128) void k_prep_kv(const float* __restrict__ times, const float* __restrict__ rels,
    const float* __restrict__ tmaxb, const float* __restrict__ Wt, const float* __restrict__ bt,
    const float* __restrict__ Wtime, const float* __restrict__ Wedge,
    __hip_bfloat16* __restrict__ kaddg, __hip_bfloat16* __restrict__ vaddg){
  __shared__ float dt_sh[KK];
  __shared__ float temb[KK][2*TFH];
  __shared__ float rl[KK][RFE];
  const int n = blockIdx.x, j = threadIdx.x;
  if (j < KK) dt_sh[j] = tmaxb[n] - times[n*KK + j];
  __syncthreads();
  {
    const int p0 = j >> 5, f = j & 31;
    const float wtf = Wt[f], btf = bt[f];
    #pragma unroll
    for (int pass=0; pass<8; ++pass){
      const int p = p0 + pass*4;
      const float hh = fmaf(dt_sh[p], wtf, btf);
      temb[p][2*f]   = __sinf(hh)*T_NORM;
      temb[p][2*f+1] = __cosf(hh)*T_NORM;
      rl[p][f] = rels[((size_t)n*KK + p)*RFE + f];
    }
  }
  __syncthreads();
  float ak[KK], av[KK];
  #pragma unroll
  for (int p=0;p<KK;p++){ ak[p]=0.f; av[p]=0.f; }
  for (int f=0; f<2*TFH; f++){
    const float wk = Wtime[f*384 + j], wv = Wtime[f*384 + 2*HH + j];
    #pragma unroll
    for (int p=0;p<KK;p++){ const float t=temb[p][f]; ak[p]=fmaf(t,wk,ak[p]); av[p]=fmaf(t,wv,av[p]); }
  }
  for (int r=0; r<RFE; r++){
    const float wk = Wedge[r*384 + j], wv = Wedge[r*384 + 2*HH + j];
    #pragma unroll
    for (int p=0;p<KK;p++){ const float t=rl[p][r]; ak[p]=fmaf(t,wk,ak[p]); av[p]=fmaf(t,wv,av[p]); }
  }
  #pragma unroll
  for (int p=0;p<KK;p++){
    kaddg[((size_t)n*KK+p)*HH + j] = __float2bfloat16(ak[p]);
    vaddg[((size_t)n*KK+p)*HH + j] = __float2bfloat16(av[p]);
  }
}

// per layer: xn = LN(h); kqv = xn@Wkqv (+ t_qq folded into q chunk)
__global__ __launch_bounds__(128) void k_ln_kqv(const float* __restrict__ Hin, const float* __restrict__ Wkqv,
                                                const float* __restrict__ g1, const float* __restrict__ b1,
                                                const float* __restrict__ tqq,
                                                float* __restrict__ XN, float* __restrict__ KQV){
  __shared__ float xs[NPB][HH];
  __shared__ float red[2];
  const int n0 = blockIdx.x*NPB, j = threadIdx.x;
  #pragma unroll
  for (int r=0;r<NPB;r++) xs[r][j] = Hin[(size_t)(n0+r)*HH + j];
  __syncthreads();
  const float gj = g1[j], bj = b1[j];
  for (int r=0;r<NPB;r++){
    const float v = xs[r][j];
    const float mn = blocksum128(v, red) * (1.f/HH);
    const float d = v - mn;
    const float var = blocksum128(d*d, red) * (1.f/HH);
    const float xnv = d * rsqrtf(var + LN_EPS) * gj + bj;
    xs[r][j] = xnv;                     // own element only; barriers protect cross-reads
    XN[(size_t)(n0+r)*HH + j] = xnv;
  }
  __syncthreads();
  float a0[NPB], a1[NPB], a2[NPB];
  #pragma unroll
  for (int r=0;r<NPB;r++){ a0[r]=0.f; a1[r]=0.f; a2[r]=0.f; }
  for (int i=0;i<HH;i++){
    const float w0 = Wkqv[i*384 + j];
    const float w1 = Wkqv[i*384 + HH + j];
    const float w2 = Wkqv[i*384 + 2*HH + j];
    #pragma unroll
    for (int r=0;r<NPB;r++){
      const float xv = xs[r][i];
      a0[r]=fmaf(xv,w0,a0[r]); a1[r]=fmaf(xv,w1,a1[r]); a2[r]=fmaf(xv,w2,a2[r]);
    }
  }
  #pragma unroll
  for (int r=0;r<NPB;r++){
    const size_t n=n0+r;
    KQV[n*384 + j]        = a0[r];
    KQV[n*384 + HH + j]   = a1[r] + tqq[n*HH+j];
    KQV[n*384 + 2*HH + j] = a2[r];
  }
}

// attention per node + h2 = attnout + xn. PRECOMP reads kadd/vadd from ws, else recompute in-block.
template<bool PRECOMP>
__global__ __launch_bounds__(128) void k_attn(const float* __restrict__ KQV, const float* __restrict__ XN,
    const float* __restrict__ tmaxb, const float* __restrict__ times, const int* __restrict__ nbrs,
    const float* __restrict__ rels, const float* __restrict__ Wt, const float* __restrict__ bt,
    const float* __restrict__ Wtime, const float* __restrict__ Wedge,
    const __hip_bfloat16* __restrict__ kaddg, const __hip_bfloat16* __restrict__ vaddg,
    float* __restrict__ H2){
  __shared__ float dt_sh[KK];
  __shared__ int valid_sh[KK];
  __shared__ int nbr_sh[KK];
  __shared__ float temb[PRECOMP?1:KK][2*TFH];
  __shared__ float rl[PRECOMP?1:KK][RFE];
  __shared__ float kadds[PRECOMP?1:KK][HH];
  __shared__ float vadds[PRECOMP?1:KK][HH];
  const int n = blockIdx.x, j = threadIdx.x;
  if (j < KK){
    const float t = times[n*KK + j];
    valid_sh[j] = (t >= START_T) && (t < END_T);
    nbr_sh[j] = nbrs[n*KK + j];
    if (!PRECOMP) dt_sh[j] = tmaxb[n] - t;
  }
  __syncthreads();
  if (!PRECOMP){
    {
      const int p0 = j >> 5, f = j & 31;
      const float wtf = Wt[f], btf = bt[f];
      #pragma unroll
      for (int pass=0; pass<8; ++pass){
        const int p = p0 + pass*4;
        const float hh = fmaf(dt_sh[p], wtf, btf);
        temb[p][2*f]   = __sinf(hh)*T_NORM;
        temb[p][2*f+1] = __cosf(hh)*T_NORM;
        rl[p][f] = rels[((size_t)n*KK + p)*RFE + f];
      }
    }
    __syncthreads();
    float ak[KK], av[KK];
    #pragma unroll
    for (int p=0;p<KK;p++){ ak[p]=0.f; av[p]=0.f; }
    for (int f=0; f<2*TFH; f++){
      const float wk = Wtime[f*384 + j], wv = Wtime[f*384 + 2*HH + j];
      #pragma unroll
      for (int p=0;p<KK;p++){ const float t=temb[p][f]; ak[p]=fmaf(t,wk,ak[p]); av[p]=fmaf(t,wv,av[p]); }
    }
    for (int r=0; r<RFE; r++){
      const float wk = Wedge[r*384 + j], wv = Wedge[r*384 + 2*HH + j];
      #pragma unroll
      for (int p=0;p<KK;p++){ const float t=rl[p][r]; ak[p]=fmaf(t,wk,ak[p]); av[p]=fmaf(t,wv,av[p]); }
    }
    #pragma unroll
    for (int p=0;p<KK;p++){ kadds[p][j]=ak[p]; vadds[p][j]=av[p]; }
    __syncthreads();
  }
  const float qv = KQV[(size_t)n*384 + HH + j];
  float m = -3.0e38f, l = 0.f, acc = 0.f;
  for (int k=0;k<KK;k++){
    if (valid_sh[k]){                       // uniform across block
      const int nbr = nbr_sh[k];
      float kaddv, vaddv;
      if (PRECOMP){
        kaddv = __bfloat162float(kaddg[((size_t)n*KK+k)*HH + j]);
        vaddv = __bfloat162float(vaddg[((size_t)n*KK+k)*HH + j]);
      } else {
        kaddv = kadds[k][j]; vaddv = vadds[k][j];
      }
      const float kv = KQV[(size_t)nbr*384 + j] + kaddv;
      float p = qv * kv;
      p += __shfl_xor(p, 8, 16);
      p += __shfl_xor(p, 4, 16);
      p += __shfl_xor(p, 2, 16);
      p += __shfl_xor(p, 1, 16);
      const float s = p * ATTN_NORM;
      const float mn = fmaxf(m, s);
      const float sc = __expf(m - mn);
      const float e  = __expf(s - mn);
      const float vv = KQV[(size_t)nbr*384 + 2*HH + j] + vaddv;
      l   = fmaf(l, sc, e);
      acc = fmaf(acc, sc, e*vv);
      m = mn;
    }
  }
  const float o = (l > 0.f) ? (acc / l) : 0.f;   // zero-valid nodes -> 0 (has gate)
  H2[(size_t)n*HH + j] = o + XN[(size_t)n*HH + j];
}

// per layer: hn = LN(h2); h_next = relu([xn,hn]@W1+bl1)@W2 + bl2 + h2
__global__ __launch_bounds__(128) void k_ffn(const float* __restrict__ XN, const float* __restrict__ H2,
    const float* __restrict__ W1, const float* __restrict__ bl1,
    const float* __restrict__ W2, const float* __restrict__ bl2,
    const float* __restrict__ g2, const float* __restrict__ b2,
    float* __restrict__ HOUT){
  __shared__ float xns[NPB][HH];
  __shared__ float hns[NPB][HH];
  __shared__ float mids[NPB][HH];
  __shared__ float red[2];
  const int n0 = blockIdx.x*NPB, j = threadIdx.x;
  #pragma unroll
  for (int r=0;r<NPB;r++){
    xns[r][j] = XN[(size_t)(n0+r)*HH + j];
    hns[r][j] = H2[(size_t)(n0+r)*HH + j];
  }
  __syncthreads();
  const float gj = g2[j], bj = b2[j];
  for (int r=0;r<NPB;r++){
    const float v = hns[r][j];
    const float mn = blocksum128(v, red)*(1.f/HH);
    const float d = v - mn;
    const float var = blocksum128(d*d, red)*(1.f/HH);
    hns[r][j] = d * rsqrtf(var + LN_EPS) * gj + bj;
  }
  __syncthreads();
  float a[NPB];
  #pragma unroll
  for (int r=0;r<NPB;r++) a[r]=0.f;
  for (int i=0;i<HH;i++){
    const float w = W1[i*HH + j];
    #pragma unroll
    for (int r=0;r<NPB;r++) a[r]=fmaf(xns[r][i], w, a[r]);
  }
  for (int i=0;i<HH;i++){
    const float w = W1[(HH+i)*HH + j];
    #pragma unroll
    for (int r=0;r<NPB;r++) a[r]=fmaf(hns[r][i], w, a[r]);
  }
  const float b1j = bl1[j];
  #pragma unroll
  for (int r=0;r<NPB;r++) mids[r][j] = fmaxf(a[r]+b1j, 0.f);
  __syncthreads();
  float o[NPB];
  #pragma unroll
  for (int r=0;r<NPB;r++) o[r]=0.f;
  for (int i=0;i<HH;i++){
    const float w = W2[i*HH + j];
    #pragma unroll
    for (int r=0;r<NPB;r++) o[r]=fmaf(mids[r][i], w, o[r]);
  }
  const float b2j = bl2[j];
  #pragma unroll
  for (int r=0;r<NPB;r++) HOUT[(size_t)(n0+r)*HH + j] = o[r] + b2j + H2[(size_t)(n0+r)*HH + j];
}

// out = h @ Wo + bo
__global__ __launch_bounds__(64) void k_out(const float* __restrict__ Hin, const float* __restrict__ Wo,
                                            const float* __restrict__ bo, float* __restrict__ OUT){
  __shared__ float xs[8][HH];
  const int n0 = blockIdx.x*8, j = threadIdx.x;
  #pragma unroll
  for (int r=0;r<8;r++){
    xs[r][j]    = Hin[(size_t)(n0+r)*HH + j];
    xs[r][j+64] = Hin[(size_t)(n0+r)*HH + 64 + j];
  }
  __syncthreads();
  float acc[8];
  #pragma unroll
  for (int r=0;r<8;r++) acc[r]=0.f;
  for (int i=0;i<HH;i++){
    const float w = Wo[i*OUTF + j];
    #pragma unroll
    for (int r=0;r<8;r++) acc[r]=fmaf(xs[r][i], w, acc[r]);
  }
  const float bj = bo[j];
  #pragma unroll
  for (int r=0;r<8;r++) OUT[(size_t)(n0+r)*OUTF + j] = acc[r] + bj;
}

extern "C" void kernel_launch(void* const* d_in, const int* in_sizes, int n_in,
                              void* d_out, int out_size, void* d_ws, size_t ws_size,
                              hipStream_t stream){
  const float* x         = (const float*)d_in[0];
  const int*   neighbors = (const int*)  d_in[1];
  const float* times     = (const float*)d_in[2];
  const float* rels      = (const float*)d_in[3];
  const float* Wp        = (const float*)d_in[4];
  const float* bp        = (const float*)d_in[5];
  const float* Wkqv      = (const float*)d_in[6];
  const float* Wt        = (const float*)d_in[7];
  const float* bt        = (const float*)d_in[8];
  const float* Wtime     = (const float*)d_in[9];
  const float* Wedge     = (const float*)d_in[10];
  const float* g1        = (const float*)d_in[11];
  const float* b1n       = (const float*)d_in[12];
  const float* g2        = (const float*)d_in[13];
  const float* b2n       = (const float*)d_in[14];
  const float* W1        = (const float*)d_in[15];
  const float* bl1       = (const float*)d_in[16];
  const float* W2        = (const float*)d_in[17];
  const float* bl2       = (const float*)d_in[18];
  const float* Wo        = (const float*)d_in[19];
  const float* bo        = (const float*)d_in[20];
  float* out = (float*)d_out;

  char* ws = (char*)d_ws;
  size_t off = 0;
  auto carve = [&](size_t bytes)->char*{
    char* p = ws + off; off = (off + bytes + 255) & ~(size_t)255; return p;
  };
  float* hA    = (float*)carve((size_t)NN*HH*4);
  float* hB    = (float*)carve((size_t)NN*HH*4);
  float* xn    = (float*)carve((size_t)NN*HH*4);
  float* h2    = (float*)carve((size_t)NN*HH*4);
  float* tqq   = (float*)carve((size_t)NN*HH*4);
  float* kqv   = (float*)carve((size_t)NN*384*4);
  float* tmaxb = (float*)carve((size_t)NN*4);
  __hip_bfloat16* kaddg = (__hip_bfloat16*)carve((size_t)NN*KK*HH*2);
  __hip_bfloat16* vaddg = (__hip_bfloat16*)carve((size_t)NN*KK*HH*2);
  const bool precomp = (ws_size >= off);   // ~205 MB: precompute layer-invariant kadd/vadd once

  k_proj<<<NN/NPB, 128, 0, stream>>>(x, Wp, bp, hA);
  k_prep_node<<<NN, 128, 0, stream>>>(times, Wt, bt, Wtime, tqq, tmaxb);
  if (precomp)
    k_prep_kv<<<NN, 128, 0, stream>>>(times, rels, tmaxb, Wt, bt, Wtime, Wedge, kaddg, vaddg);

  float* cur = hA; float* nxt = hB;
  for (int layer=0; layer<2; ++layer){
    k_ln_kqv<<<NN/NPB, 128, 0, stream>>>(cur, Wkqv, g1, b1n, tqq, xn, kqv);
    if (precomp)
      k_attn<true><<<NN, 128, 0, stream>>>(kqv, xn, tmaxb, times, neighbors, rels,
                                           Wt, bt, Wtime, Wedge, kaddg, vaddg, h2);
    else
      k_attn<false><<<NN, 128, 0, stream>>>(kqv, xn, tmaxb, times, neighbors, rels,
                                            Wt, bt, Wtime, Wedge, kaddg, vaddg, h2);
    k_ffn<<<NN/NPB, 128, 0, stream>>>(xn, h2, W1, bl1, W2, bl2, g2, b2n, nxt);
    float* t = cur; cur = nxt; nxt = t;
  }
  k_out<<<NN/8, 64, 0, stream>>>(cur, Wo, bo, out);
}

// Round 2
// 484.737 us; speedup vs baseline: 1.3648x; 1.3648x over previous
//
#include <hip/hip_runtime.h>
#include <hip/hip_bf16.h>

#define NN 10000
#define KK 32
#define HH 128
#define TFH 32      // T_F/2
#define RFE 32
#define OUTF 64
#define START_T 0.25f
#define END_T 0.75f
#define ATTN_NORM 0.25f
#define T_NORM 0.17677669529663687f   // sqrt(1/32)
#define LN_EPS 1e-5f
#define NPB 16

typedef __attribute__((ext_vector_type(4))) float f32x4;
typedef __attribute__((ext_vector_type(8))) short bf16x8;

__device__ __forceinline__ ushort f2bf(float x){
  __hip_bfloat16 b = __float2bfloat16(x);
  return *(ushort*)&b;
}

__device__ __forceinline__ float blocksum128(float v, float* red){
  #pragma unroll
  for (int off=32; off; off>>=1) v += __shfl_down(v, off, 64);
  __syncthreads();
  if ((threadIdx.x & 63)==0) red[threadIdx.x>>6] = v;
  __syncthreads();
  return red[0]+red[1];
}

// h = relu(x @ Wp + bp)
__global__ __launch_bounds__(128) void k_proj(const float* __restrict__ X, const float* __restrict__ W,
                                              const float* __restrict__ b, float* __restrict__ Y){
  __shared__ float xs[NPB][HH];
  const int n0 = blockIdx.x*NPB, j = threadIdx.x;
  #pragma unroll
  for (int r=0;r<NPB;r++) xs[r][j] = X[(size_t)(n0+r)*HH + j];
  __syncthreads();
  float acc[NPB];
  #pragma unroll
  for (int r=0;r<NPB;r++) acc[r]=0.f;
  for (int i=0;i<HH;i++){
    const float w = W[i*HH + j];
    #pragma unroll
    for (int r=0;r<NPB;r++) acc[r] = fmaf(xs[r][i], w, acc[r]);
  }
  const float bj = b[j];
  #pragma unroll
  for (int r=0;r<NPB;r++) Y[(size_t)(n0+r)*HH + j] = fmaxf(acc[r]+bj, 0.f);
}

// per node: tmax (masked max of times, floor START_T) and t_qq = (t2v(tmax-START_T) @ Wtime)[:, H:2H]
__global__ __launch_bounds__(128) void k_prep_node(const float* __restrict__ times, const float* __restrict__ Wt,
                                                   const float* __restrict__ bt, const float* __restrict__ Wtime,
                                                   float* __restrict__ tqq, float* __restrict__ tmaxb){
  __shared__ float temb[2*TFH];
  __shared__ float tm_sh;
  const int n = blockIdx.x, j = threadIdx.x;
  if (j < KK){
    float t = times[n*KK + j];
    bool valid = (t >= START_T) && (t < END_T);
    float val = valid ? t : START_T;
    #pragma unroll
    for (int off=16; off; off>>=1) val = fmaxf(val, __shfl_xor(val, off, 32));
    if (j==0){ tm_sh = val; tmaxb[n] = val; }
  }
  __syncthreads();
  if (j < TFH){
    float hh = fmaf(tm_sh - START_T, Wt[j], bt[j]);
    temb[2*j]   = __sinf(hh)*T_NORM;
    temb[2*j+1] = __cosf(hh)*T_NORM;
  }
  __syncthreads();
  float acc = 0.f;
  #pragma unroll
  for (int f=0; f<2*TFH; f++) acc = fmaf(temb[f], Wtime[f*384 + HH + j], acc);
  tqq[n*HH + j] = acc;
}

// once: WcT[256][96] bf16 — combined (Wtime|Wedge) k- and v-chunks, transposed.
// col c<128 -> k-chunk col c ; c>=128 -> v-chunk col (c-128)  (i.e. source col c+128... c+256-128)
__global__ __launch_bounds__(256) void k_prep_w(const float* __restrict__ Wtime, const float* __restrict__ Wedge,
                                                ushort* __restrict__ WcT){
  const int r = blockIdx.x, c = threadIdx.x;       // r in [0,96), c in [0,256)
  const int cc = (c < 128) ? c : (c + 128);        // v-chunk source col = (c-128)+256
  const float v = (r < 64) ? Wtime[r*384 + cc] : Wedge[(r-64)*384 + cc];
  WcT[c*96 + r] = f2bf(v);
}

// once: kadd/vadd for all (n,k) pairs via MFMA.  F[64x96] @ Wc[96x256] per block (2 nodes).
#define MT 64
#define LDA 104      // 96 + 8 pad (bf16 elems) -> stride 208B kills 8-way bank conflict
__global__ __launch_bounds__(256) void k_prep_kv_mfma(
    const float* __restrict__ times, const float* __restrict__ rels, const float* __restrict__ tmaxb,
    const float* __restrict__ Wt, const float* __restrict__ bt, const ushort* __restrict__ WcT,
    __hip_bfloat16* __restrict__ kaddg, __hip_bfloat16* __restrict__ vaddg){
  __shared__ ushort Fa[MT*LDA];       // 13.3 KB
  __shared__ ushort Bs[256*LDA];      // 53.2 KB
  __shared__ float dt_sh[MT];
  const int tid = threadIdx.x;
  const int node0 = blockIdx.x*2;
  // stage B (bf16 weights) 256 rows x 12 uint4
  {
    const uint4* src = (const uint4*)WcT;
    #pragma unroll
    for (int i0=0; i0<12; ++i0){
      const int i = tid + i0*256;
      const int row = i/12, seg = i%12;
      *(uint4*)&Bs[row*LDA + seg*8] = src[i];
    }
  }
  if (tid < MT){
    const int node = node0 + (tid>>5);
    dt_sh[tid] = tmaxb[node] - times[node*KK + (tid&31)];
  }
  __syncthreads();
  // temb: 64 pairs x 32 freqs, interleaved sin/cos -> Fa cols [0,64)
  #pragma unroll
  for (int s0=0; s0<8; ++s0){
    const int s = tid + s0*256;
    const int p = s>>5, f = s&31;
    const float hh = fmaf(dt_sh[p], Wt[f], bt[f]);
    ushort2 pk;
    pk.x = f2bf(__sinf(hh)*T_NORM);
    pk.y = f2bf(__cosf(hh)*T_NORM);
    *(ushort2*)&Fa[p*LDA + 2*f] = pk;
  }
  // rels -> Fa cols [64,96)
  #pragma unroll
  for (int s0=0; s0<2; ++s0){
    const int i = tid + s0*256;
    const int p = i>>3, seg = i&7;
    const float4 rv = *(const float4*)&rels[((size_t)node0*KK + p)*RFE + seg*4];
    ushort4 w; w.x=f2bf(rv.x); w.y=f2bf(rv.y); w.z=f2bf(rv.z); w.w=f2bf(rv.w);
    *(ushort4*)&Fa[p*LDA + 64 + seg*4] = w;
  }
  __syncthreads();
  const int wave = tid>>6, lane = tid&63;
  const int lr = lane&15, lk = (lane>>4)*8;
  f32x4 acc[4][4];
  #pragma unroll
  for (int m=0;m<4;m++)
    #pragma unroll
    for (int n=0;n<4;n++) acc[m][n] = (f32x4){0.f,0.f,0.f,0.f};
  #pragma unroll
  for (int kk=0; kk<3; ++kk){
    const int k0 = kk*32;
    bf16x8 a[4], b[4];
    #pragma unroll
    for (int m=0;m<4;m++) a[m] = *(const bf16x8*)&Fa[(m*16 + lr)*LDA + k0 + lk];
    #pragma unroll
    for (int n=0;n<4;n++) b[n] = *(const bf16x8*)&Bs[(wave*64 + n*16 + lr)*LDA + k0 + lk];
    #pragma unroll
    for (int m=0;m<4;m++)
      #pragma unroll
      for (int n=0;n<4;n++)
        acc[m][n] = __builtin_amdgcn_mfma_f32_16x16x32_bf16(a[m], b[n], acc[m][n], 0,0,0);
  }
  // C layout: col = lane&15, row = (lane>>4)*4 + reg   [m89/m91]
  const int rbase = (lane>>4)*4;
  #pragma unroll
  for (int n=0;n<4;n++){
    const int c = wave*64 + n*16 + lr;
    __hip_bfloat16* dst = (c < 128) ? kaddg : vaddg;
    const int cj = c & 127;
    #pragma unroll
    for (int m=0;m<4;m++){
      #pragma unroll
      for (int r=0;r<4;r++){
        const size_t P = (size_t)node0*KK + m*16 + rbase + r;
        dst[P*HH + cj] = __float2bfloat16(acc[m][n][r]);
      }
    }
  }
}

// per layer: xn = LN(h); kqv = xn@Wkqv (+ t_qq folded into q chunk)
__global__ __launch_bounds__(128) void k_ln_kqv(const float* __restrict__ Hin, const float* __restrict__ Wkqv,
                                                const float* __restrict__ g1, const float* __restrict__ b1,
                                                const float* __restrict__ tqq,
                                                float* __restrict__ XN, float* __restrict__ KQV){
  __shared__ float xs[NPB][HH];
  __shared__ float red[2];
  const int n0 = blockIdx.x*NPB, j = threadIdx.x;
  #pragma unroll
  for (int r=0;r<NPB;r++) xs[r][j] = Hin[(size_t)(n0+r)*HH + j];
  __syncthreads();
  const float gj = g1[j], bj = b1[j];
  for (int r=0;r<NPB;r++){
    const float v = xs[r][j];
    const float mn = blocksum128(v, red) * (1.f/HH);
    const float d = v - mn;
    const float var = blocksum128(d*d, red) * (1.f/HH);
    const float xnv = d * rsqrtf(var + LN_EPS) * gj + bj;
    xs[r][j] = xnv;
    XN[(size_t)(n0+r)*HH + j] = xnv;
  }
  __syncthreads();
  float a0[NPB], a1[NPB], a2[NPB];
  #pragma unroll
  for (int r=0;r<NPB;r++){ a0[r]=0.f; a1[r]=0.f; a2[r]=0.f; }
  for (int i=0;i<HH;i++){
    const float w0 = Wkqv[i*384 + j];
    const float w1 = Wkqv[i*384 + HH + j];
    const float w2 = Wkqv[i*384 + 2*HH + j];
    #pragma unroll
    for (int r=0;r<NPB;r++){
      const float xv = xs[r][i];
      a0[r]=fmaf(xv,w0,a0[r]); a1[r]=fmaf(xv,w1,a1[r]); a2[r]=fmaf(xv,w2,a2[r]);
    }
  }
  #pragma unroll
  for (int r=0;r<NPB;r++){
    const size_t n=n0+r;
    KQV[n*384 + j]        = a0[r];
    KQV[n*384 + HH + j]   = a1[r] + tqq[n*HH+j];
    KQV[n*384 + 2*HH + j] = a2[r];
  }
}

// attention per node + h2 = attnout + xn.
template<bool PRECOMP>
__global__ __launch_bounds__(128) void k_attn(const float* __restrict__ KQV, const float* __restrict__ XN,
    const float* __restrict__ tmaxb, const float* __restrict__ times, const int* __restrict__ nbrs,
    const float* __restrict__ rels, const float* __restrict__ Wt, const float* __restrict__ bt,
    const float* __restrict__ Wtime, const float* __restrict__ Wedge,
    const __hip_bfloat16* __restrict__ kaddg, const __hip_bfloat16* __restrict__ vaddg,
    float* __restrict__ H2){
  __shared__ float dt_sh[KK];
  __shared__ int valid_sh[KK];
  __shared__ int nbr_sh[KK];
  __shared__ float temb[PRECOMP?1:KK][2*TFH];
  __shared__ float rl[PRECOMP?1:KK][RFE];
  __shared__ float kadds[PRECOMP?1:KK][HH];
  __shared__ float vadds[PRECOMP?1:KK][HH];
  const int n = blockIdx.x, j = threadIdx.x;
  if (j < KK){
    const float t = times[n*KK + j];
    valid_sh[j] = (t >= START_T) && (t < END_T);
    nbr_sh[j] = nbrs[n*KK + j];
    if (!PRECOMP) dt_sh[j] = tmaxb[n] - t;
  }
  __syncthreads();
  if (!PRECOMP){
    {
      const int p0 = j >> 5, f = j & 31;
      const float wtf = Wt[f], btf = bt[f];
      #pragma unroll
      for (int pass=0; pass<8; ++pass){
        const int p = p0 + pass*4;
        const float hh = fmaf(dt_sh[p], wtf, btf);
        temb[p][2*f]   = __sinf(hh)*T_NORM;
        temb[p][2*f+1] = __cosf(hh)*T_NORM;
        rl[p][f] = rels[((size_t)n*KK + p)*RFE + f];
      }
    }
    __syncthreads();
    float ak[KK], av[KK];
    #pragma unroll
    for (int p=0;p<KK;p++){ ak[p]=0.f; av[p]=0.f; }
    for (int f=0; f<2*TFH; f++){
      const float wk = Wtime[f*384 + j], wv = Wtime[f*384 + 2*HH + j];
      #pragma unroll
      for (int p=0;p<KK;p++){ const float t=temb[p][f]; ak[p]=fmaf(t,wk,ak[p]); av[p]=fmaf(t,wv,av[p]); }
    }
    for (int r=0; r<RFE; r++){
      const float wk = Wedge[r*384 + j], wv = Wedge[r*384 + 2*HH + j];
      #pragma unroll
      for (int p=0;p<KK;p++){ const float t=rl[p][r]; ak[p]=fmaf(t,wk,ak[p]); av[p]=fmaf(t,wv,av[p]); }
    }
    #pragma unroll
    for (int p=0;p<KK;p++){ kadds[p][j]=ak[p]; vadds[p][j]=av[p]; }
    __syncthreads();
  }
  const float qv = KQV[(size_t)n*384 + HH + j];
  float m = -3.0e38f, l = 0.f, acc = 0.f;
  for (int k=0;k<KK;k++){
    if (valid_sh[k]){
      const int nbr = nbr_sh[k];
      float kaddv, vaddv;
      if (PRECOMP){
        kaddv = __bfloat162float(kaddg[((size_t)n*KK+k)*HH + j]);
        vaddv = __bfloat162float(vaddg[((size_t)n*KK+k)*HH + j]);
      } else {
        kaddv = kadds[k][j]; vaddv = vadds[k][j];
      }
      const float kv = KQV[(size_t)nbr*384 + j] + kaddv;
      float p = qv * kv;
      p += __shfl_xor(p, 8, 16);
      p += __shfl_xor(p, 4, 16);
      p += __shfl_xor(p, 2, 16);
      p += __shfl_xor(p, 1, 16);
      const float s = p * ATTN_NORM;
      const float mn = fmaxf(m, s);
      const float sc = __expf(m - mn);
      const float e  = __expf(s - mn);
      const float vv = KQV[(size_t)nbr*384 + 2*HH + j] + vaddv;
      l   = fmaf(l, sc, e);
      acc = fmaf(acc, sc, e*vv);
      m = mn;
    }
  }
  const float o = (l > 0.f) ? (acc / l) : 0.f;
  H2[(size_t)n*HH + j] = o + XN[(size_t)n*HH + j];
}

// per layer: hn = LN(h2); h_next = relu([xn,hn]@W1+bl1)@W2 + bl2 + h2
__global__ __launch_bounds__(128) void k_ffn(const float* __restrict__ XN, const float* __restrict__ H2,
    const float* __restrict__ W1, const float* __restrict__ bl1,
    const float* __restrict__ W2, const float* __restrict__ bl2,
    const float* __restrict__ g2, const float* __restrict__ b2,
    float* __restrict__ HOUT){
  __shared__ float xns[NPB][HH];
  __shared__ float hns[NPB][HH];
  __shared__ float mids[NPB][HH];
  __shared__ float red[2];
  const int n0 = blockIdx.x*NPB, j = threadIdx.x;
  #pragma unroll
  for (int r=0;r<NPB;r++){
    xns[r][j] = XN[(size_t)(n0+r)*HH + j];
    hns[r][j] = H2[(size_t)(n0+r)*HH + j];
  }
  __syncthreads();
  const float gj = g2[j], bj = b2[j];
  for (int r=0;r<NPB;r++){
    const float v = hns[r][j];
    const float mn = blocksum128(v, red)*(1.f/HH);
    const float d = v - mn;
    const float var = blocksum128(d*d, red)*(1.f/HH);
    hns[r][j] = d * rsqrtf(var + LN_EPS) * gj + bj;
  }
  __syncthreads();
  float a[NPB];
  #pragma unroll
  for (int r=0;r<NPB;r++) a[r]=0.f;
  for (int i=0;i<HH;i++){
    const float w = W1[i*HH + j];
    #pragma unroll
    for (int r=0;r<NPB;r++) a[r]=fmaf(xns[r][i], w, a[r]);
  }
  for (int i=0;i<HH;i++){
    const float w = W1[(HH+i)*HH + j];
    #pragma unroll
    for (int r=0;r<NPB;r++) a[r]=fmaf(hns[r][i], w, a[r]);
  }
  const float b1j = bl1[j];
  #pragma unroll
  for (int r=0;r<NPB;r++) mids[r][j] = fmaxf(a[r]+b1j, 0.f);
  __syncthreads();
  float o[NPB];
  #pragma unroll
  for (int r=0;r<NPB;r++) o[r]=0.f;
  for (int i=0;i<HH;i++){
    const float w = W2[i*HH + j];
    #pragma unroll
    for (int r=0;r<NPB;r++) o[r]=fmaf(mids[r][i], w, o[r]);
  }
  const float b2j = bl2[j];
  #pragma unroll
  for (int r=0;r<NPB;r++) HOUT[(size_t)(n0+r)*HH + j] = o[r] + b2j + H2[(size_t)(n0+r)*HH + j];
}

// out = h @ Wo + bo
__global__ __launch_bounds__(64) void k_out(const float* __restrict__ Hin, const float* __restrict__ Wo,
                                            const float* __restrict__ bo, float* __restrict__ OUT){
  __shared__ float xs[8][HH];
  const int n0 = blockIdx.x*8, j = threadIdx.x;
  #pragma unroll
  for (int r=0;r<8;r++){
    xs[r][j]    = Hin[(size_t)(n0+r)*HH + j];
    xs[r][j+64] = Hin[(size_t)(n0+r)*HH + 64 + j];
  }
  __syncthreads();
  float acc[8];
  #pragma unroll
  for (int r=0;r<8;r++) acc[r]=0.f;
  for (int i=0;i<HH;i++){
    const float w = Wo[i*OUTF + j];
    #pragma unroll
    for (int r=0;r<8;r++) acc[r]=fmaf(xs[r][i], w, acc[r]);
  }
  const float bj = bo[j];
  #pragma unroll
  for (int r=0;r<8;r++) OUT[(size_t)(n0+r)*OUTF + j] = acc[r] + bj;
}

extern "C" void kernel_launch(void* const* d_in, const int* in_sizes, int n_in,
                              void* d_out, int out_size, void* d_ws, size_t ws_size,
                              hipStream_t stream){
  const float* x         = (const float*)d_in[0];
  const int*   neighbors = (const int*)  d_in[1];
  const float* times     = (const float*)d_in[2];
  const float* rels      = (const float*)d_in[3];
  const float* Wp        = (const float*)d_in[4];
  const float* bp        = (const float*)d_in[5];
  const float* Wkqv      = (const float*)d_in[6];
  const float* Wt        = (const float*)d_in[7];
  const float* bt        = (const float*)d_in[8];
  const float* Wtime     = (const float*)d_in[9];
  const float* Wedge     = (const float*)d_in[10];
  const float* g1        = (const float*)d_in[11];
  const float* b1n       = (const float*)d_in[12];
  const float* g2        = (const float*)d_in[13];
  const float* b2n       = (const float*)d_in[14];
  const float* W1        = (const float*)d_in[15];
  const float* bl1       = (const float*)d_in[16];
  const float* W2        = (const float*)d_in[17];
  const float* bl2       = (const float*)d_in[18];
  const float* Wo        = (const float*)d_in[19];
  const float* bo        = (const float*)d_in[20];
  float* out = (float*)d_out;

  char* ws = (char*)d_ws;
  size_t off = 0;
  auto carve = [&](size_t bytes)->char*{
    char* p = ws + off; off = (off + bytes + 255) & ~(size_t)255; return p;
  };
  float* hA    = (float*)carve((size_t)NN*HH*4);
  float* hB    = (float*)carve((size_t)NN*HH*4);
  float* xn    = (float*)carve((size_t)NN*HH*4);
  float* h2    = (float*)carve((size_t)NN*HH*4);
  float* tqq   = (float*)carve((size_t)NN*HH*4);
  float* kqv   = (float*)carve((size_t)NN*384*4);
  float* tmaxb = (float*)carve((size_t)NN*4);
  ushort* WcTg = (ushort*)carve((size_t)256*96*2);
  __hip_bfloat16* kaddg = (__hip_bfloat16*)carve((size_t)NN*KK*HH*2);
  __hip_bfloat16* vaddg = (__hip_bfloat16*)carve((size_t)NN*KK*HH*2);
  const bool precomp = (ws_size >= off);

  k_proj<<<NN/NPB, 128, 0, stream>>>(x, Wp, bp, hA);
  k_prep_node<<<NN, 128, 0, stream>>>(times, Wt, bt, Wtime, tqq, tmaxb);
  if (precomp){
    k_prep_w<<<96, 256, 0, stream>>>(Wtime, Wedge, WcTg);
    k_prep_kv_mfma<<<NN/2, 256, 0, stream>>>(times, rels, tmaxb, Wt, bt, WcTg, kaddg, vaddg);
  }

  float* cur = hA; float* nxt = hB;
  for (int layer=0; layer<2; ++layer){
    k_ln_kqv<<<NN/NPB, 128, 0, stream>>>(cur, Wkqv, g1, b1n, tqq, xn, kqv);
    if (precomp)
      k_attn<true><<<NN, 128, 0, stream>>>(kqv, xn, tmaxb, times, neighbors, rels,
                                           Wt, bt, Wtime, Wedge, kaddg, vaddg, h2);
    else
      k_attn<false><<<NN, 128, 0, stream>>>(kqv, xn, tmaxb, times, neighbors, rels,
                                            Wt, bt, Wtime, Wedge, kaddg, vaddg, h2);
    k_ffn<<<NN/NPB, 128, 0, stream>>>(xn, h2, W1, bl1, W2, bl2, g2, b2n, nxt);
    float* t = cur; cur = nxt; nxt = t;
  }
  k_out<<<NN/8, 64, 0, stream>>>(cur, Wo, bo, out);
}

// Round 3
// 221.607 us; speedup vs baseline: 2.9853x; 2.1874x over previous
//
#include <hip/hip_runtime.h>
#include <hip/hip_bf16.h>

#define NN 10000
#define KK 32
#define HH 128
#define TFH 32      // T_F/2
#define RFE 32
#define OUTF 64
#define START_T 0.25f
#define END_T 0.75f
#define ATTN_NORM 0.25f
#define T_NORM 0.17677669529663687f   // sqrt(1/32)
#define LN_EPS 1e-5f

typedef __attribute__((ext_vector_type(4))) float f32x4;
typedef __attribute__((ext_vector_type(8))) short bf16x8;

__device__ __forceinline__ ushort f2bf(float x){
  __hip_bfloat16 b = __float2bfloat16(x);
  return *(ushort*)&b;
}

__device__ __forceinline__ float blocksum128(float v, float* red){
  #pragma unroll
  for (int off=32; off; off>>=1) v += __shfl_down(v, off, 64);
  __syncthreads();
  if ((threadIdx.x & 63)==0) red[threadIdx.x>>6] = v;
  __syncthreads();
  return red[0]+red[1];
}

__device__ __forceinline__ float groupsum32(float v){
  v += __shfl_xor(v, 16, 32);
  v += __shfl_xor(v, 8, 32);
  v += __shfl_xor(v, 4, 32);
  v += __shfl_xor(v, 2, 32);
  v += __shfl_xor(v, 1, 32);
  return v;
}

// ---------- one-time weight transposes to bf16 [N][K] ----------
__global__ __launch_bounds__(256) void k_prep_wT(const float* __restrict__ Wp, const float* __restrict__ Wkqv,
    const float* __restrict__ W1, const float* __restrict__ W2, const float* __restrict__ Wo,
    ushort* __restrict__ WpT, ushort* __restrict__ WkqvT, ushort* __restrict__ W1T,
    ushort* __restrict__ W2T, ushort* __restrict__ WoT){
  int id = blockIdx.x*256 + threadIdx.x;
  if (id < 16384){ int n=id>>7, k=id&127; WpT[id]=f2bf(Wp[k*HH+n]); return; }
  id -= 16384;
  if (id < 49152){ int n=id>>7, k=id&127; WkqvT[id]=f2bf(Wkqv[k*384+n]); return; }
  id -= 49152;
  if (id < 32768){ int n=id>>8, k=id&255; W1T[id]=f2bf(W1[k*HH+n]); return; }
  id -= 32768;
  if (id < 16384){ int n=id>>7, k=id&127; W2T[id]=f2bf(W2[k*HH+n]); return; }
  id -= 16384;
  if (id < 8192){ int n=id>>7, k=id&127; WoT[id]=f2bf(Wo[k*OUTF+n]); }
}

// WcT[256][96] bf16 — combined (Wtime|Wedge) k- and v-chunks, transposed.
__global__ __launch_bounds__(256) void k_prep_w(const float* __restrict__ Wtime, const float* __restrict__ Wedge,
                                                ushort* __restrict__ WcT){
  const int r = blockIdx.x, c = threadIdx.x;       // r in [0,96), c in [0,256)
  const int cc = (c < 128) ? c : (c + 128);
  const float v = (r < 64) ? Wtime[r*384 + cc] : Wedge[(r-64)*384 + cc];
  WcT[c*96 + r] = f2bf(v);
}

// ---------- h = relu(x @ Wp + bp), MFMA ----------
#define LDA1 136   // 128+8 pad (ushorts)
__global__ __launch_bounds__(256) void k_proj_mfma(const float* __restrict__ X, const ushort* __restrict__ WpT,
                                                   const float* __restrict__ bp, float* __restrict__ Y){
  __shared__ ushort As[16*LDA1];
  const int tid = threadIdx.x, n0 = blockIdx.x*16;
  #pragma unroll
  for (int p=0;p<2;++p){
    const int idx = tid + p*256;           // 512 float4 total
    const int row = idx>>5, c4 = (idx&31)*4;
    const float4 v = *(const float4*)&X[(size_t)(n0+row)*HH + c4];
    ushort4 pk = make_ushort4(f2bf(v.x), f2bf(v.y), f2bf(v.z), f2bf(v.w));
    *(ushort4*)&As[row*LDA1 + c4] = pk;
  }
  __syncthreads();
  const int w = tid>>6, lane = tid&63;
  const int lr = lane&15, lk8 = (lane>>4)*8, rbase = (lane>>4)*4;
  bf16x8 a[4];
  #pragma unroll
  for (int kk=0;kk<4;kk++) a[kk] = *(const bf16x8*)&As[lr*LDA1 + kk*32 + lk8];
  f32x4 acc[2];
  #pragma unroll
  for (int nt=0;nt<2;nt++) acc[nt] = (f32x4){0.f,0.f,0.f,0.f};
  #pragma unroll
  for (int nt=0;nt<2;nt++){
    const int n = w*2 + nt;
    #pragma unroll
    for (int kk=0;kk<4;kk++){
      bf16x8 b = *(const bf16x8*)&WpT[(n*16+lr)*HH + kk*32 + lk8];
      acc[nt] = __builtin_amdgcn_mfma_f32_16x16x32_bf16(a[kk], b, acc[nt],0,0,0);
    }
  }
  #pragma unroll
  for (int nt=0;nt<2;nt++){
    const int c = (w*2+nt)*16 + lr;
    const float bj = bp[c];
    #pragma unroll
    for (int r=0;r<4;r++)
      Y[(size_t)(n0 + rbase + r)*HH + c] = fmaxf(acc[nt][r] + bj, 0.f);
  }
}

// ---------- per node: tmax and t_qq ----------
__global__ __launch_bounds__(128) void k_prep_node(const float* __restrict__ times, const float* __restrict__ Wt,
                                                   const float* __restrict__ bt, const float* __restrict__ Wtime,
                                                   float* __restrict__ tqq, float* __restrict__ tmaxb){
  __shared__ float temb[2*TFH];
  __shared__ float tm_sh;
  const int n = blockIdx.x, j = threadIdx.x;
  if (j < KK){
    float t = times[n*KK + j];
    bool valid = (t >= START_T) && (t < END_T);
    float val = valid ? t : START_T;
    #pragma unroll
    for (int off=16; off; off>>=1) val = fmaxf(val, __shfl_xor(val, off, 32));
    if (j==0){ tm_sh = val; tmaxb[n] = val; }
  }
  __syncthreads();
  if (j < TFH){
    float hh = fmaf(tm_sh - START_T, Wt[j], bt[j]);
    temb[2*j]   = __sinf(hh)*T_NORM;
    temb[2*j+1] = __cosf(hh)*T_NORM;
  }
  __syncthreads();
  float acc = 0.f;
  #pragma unroll
  for (int f=0; f<2*TFH; f++) acc = fmaf(temb[f], Wtime[f*384 + HH + j], acc);
  tqq[n*HH + j] = acc;
}

// ---------- once: kadd/vadd via MFMA ----------
#define MT 64
#define LDA 104
__global__ __launch_bounds__(256) void k_prep_kv_mfma(
    const float* __restrict__ times, const float* __restrict__ rels, const float* __restrict__ tmaxb,
    const float* __restrict__ Wt, const float* __restrict__ bt, const ushort* __restrict__ WcT,
    __hip_bfloat16* __restrict__ kaddg, __hip_bfloat16* __restrict__ vaddg){
  __shared__ ushort Fa[MT*LDA];
  __shared__ ushort Bs[256*LDA];
  __shared__ float dt_sh[MT];
  const int tid = threadIdx.x;
  const int node0 = blockIdx.x*2;
  {
    const uint4* src = (const uint4*)WcT;
    #pragma unroll
    for (int i0=0; i0<12; ++i0){
      const int i = tid + i0*256;
      const int row = i/12, seg = i%12;
      *(uint4*)&Bs[row*LDA + seg*8] = src[i];
    }
  }
  if (tid < MT){
    const int node = node0 + (tid>>5);
    dt_sh[tid] = tmaxb[node] - times[node*KK + (tid&31)];
  }
  __syncthreads();
  #pragma unroll
  for (int s0=0; s0<8; ++s0){
    const int s = tid + s0*256;
    const int p = s>>5, f = s&31;
    const float hh = fmaf(dt_sh[p], Wt[f], bt[f]);
    ushort2 pk;
    pk.x = f2bf(__sinf(hh)*T_NORM);
    pk.y = f2bf(__cosf(hh)*T_NORM);
    *(ushort2*)&Fa[p*LDA + 2*f] = pk;
  }
  #pragma unroll
  for (int s0=0; s0<2; ++s0){
    const int i = tid + s0*256;
    const int p = i>>3, seg = i&7;
    const float4 rv = *(const float4*)&rels[((size_t)node0*KK + p)*RFE + seg*4];
    ushort4 w2; w2.x=f2bf(rv.x); w2.y=f2bf(rv.y); w2.z=f2bf(rv.z); w2.w=f2bf(rv.w);
    *(ushort4*)&Fa[p*LDA + 64 + seg*4] = w2;
  }
  __syncthreads();
  const int wave = tid>>6, lane = tid&63;
  const int lr = lane&15, lk = (lane>>4)*8;
  f32x4 acc[4][4];
  #pragma unroll
  for (int m=0;m<4;m++)
    #pragma unroll
    for (int n=0;n<4;n++) acc[m][n] = (f32x4){0.f,0.f,0.f,0.f};
  #pragma unroll
  for (int kk=0; kk<3; ++kk){
    const int k0 = kk*32;
    bf16x8 a[4], b[4];
    #pragma unroll
    for (int m=0;m<4;m++) a[m] = *(const bf16x8*)&Fa[(m*16 + lr)*LDA + k0 + lk];
    #pragma unroll
    for (int n=0;n<4;n++) b[n] = *(const bf16x8*)&Bs[(wave*64 + n*16 + lr)*LDA + k0 + lk];
    #pragma unroll
    for (int m=0;m<4;m++)
      #pragma unroll
      for (int n=0;n<4;n++)
        acc[m][n] = __builtin_amdgcn_mfma_f32_16x16x32_bf16(a[m], b[n], acc[m][n], 0,0,0);
  }
  const int rbase = (lane>>4)*4;
  #pragma unroll
  for (int n=0;n<4;n++){
    const int c = wave*64 + n*16 + lr;
    __hip_bfloat16* dst = (c < 128) ? kaddg : vaddg;
    const int cj = c & 127;
    #pragma unroll
    for (int m=0;m<4;m++){
      #pragma unroll
      for (int r=0;r<4;r++){
        const size_t P = (size_t)node0*KK + m*16 + rbase + r;
        dst[P*HH + cj] = __float2bfloat16(acc[m][n][r]);
      }
    }
  }
}

// ---------- per layer: LN + kqv GEMM (MFMA) ----------
__global__ __launch_bounds__(256) void k_ln_kqv_mfma(const float* __restrict__ Hin, const ushort* __restrict__ WkqvT,
    const float* __restrict__ g1, const float* __restrict__ b1, const float* __restrict__ tqq,
    float* __restrict__ XN, ushort* __restrict__ xnb, float* __restrict__ KQV){
  __shared__ ushort As[16*LDA1];
  const int tid = threadIdx.x, n0 = blockIdx.x*16;
  const int grp = tid>>5, gl = tid&31;
  {
    const float4 gv = *(const float4*)&g1[gl*4];
    const float4 bv = *(const float4*)&b1[gl*4];
    #pragma unroll
    for (int rr=0; rr<2; ++rr){
      const int row = grp + rr*8;
      const int node = n0 + row;
      float4 hv = *(const float4*)&Hin[(size_t)node*HH + gl*4];
      float s = hv.x+hv.y+hv.z+hv.w;
      s = groupsum32(s);
      const float mean = s*(1.f/HH);
      const float dx=hv.x-mean, dy=hv.y-mean, dz=hv.z-mean, dw=hv.w-mean;
      float vs = dx*dx+dy*dy+dz*dz+dw*dw;
      vs = groupsum32(vs);
      const float rstd = rsqrtf(vs*(1.f/HH)+LN_EPS);
      const float x0=dx*rstd*gv.x+bv.x, x1=dy*rstd*gv.y+bv.y, x2=dz*rstd*gv.z+bv.z, x3=dw*rstd*gv.w+bv.w;
      ushort4 pk = make_ushort4(f2bf(x0), f2bf(x1), f2bf(x2), f2bf(x3));
      *(ushort4*)&As[row*LDA1 + gl*4] = pk;
      *(float4*)&XN[(size_t)node*HH + gl*4] = make_float4(x0,x1,x2,x3);
      *(ushort4*)&xnb[(size_t)node*HH + gl*4] = pk;
    }
  }
  __syncthreads();
  const int w = tid>>6, lane = tid&63;
  const int lr = lane&15, lk8 = (lane>>4)*8, rbase = (lane>>4)*4;
  bf16x8 a[4];
  #pragma unroll
  for (int kk=0;kk<4;kk++) a[kk] = *(const bf16x8*)&As[lr*LDA1 + kk*32 + lk8];
  f32x4 acc[6];
  #pragma unroll
  for (int nt=0;nt<6;nt++) acc[nt] = (f32x4){0.f,0.f,0.f,0.f};
  #pragma unroll
  for (int nt=0;nt<6;nt++){
    const int n = w*6 + nt;
    #pragma unroll
    for (int kk=0;kk<4;kk++){
      bf16x8 b = *(const bf16x8*)&WkqvT[(n*16+lr)*HH + kk*32 + lk8];
      acc[nt] = __builtin_amdgcn_mfma_f32_16x16x32_bf16(a[kk], b, acc[nt],0,0,0);
    }
  }
  #pragma unroll
  for (int nt=0;nt<6;nt++){
    const int c = (w*6+nt)*16 + lr;
    #pragma unroll
    for (int r=0;r<4;r++){
      const int node = n0 + rbase + r;
      float v = acc[nt][r];
      if (c >= HH && c < 2*HH) v += tqq[(size_t)node*HH + (c-HH)];
      KQV[(size_t)node*384 + c] = v;
    }
  }
}

// ---------- attention per node + h2 = attnout + xn; epilogue LN -> hnb ----------
template<bool PRECOMP>
__global__ __launch_bounds__(128) void k_attn(const float* __restrict__ KQV, const float* __restrict__ XN,
    const float* __restrict__ tmaxb, const float* __restrict__ times, const int* __restrict__ nbrs,
    const float* __restrict__ rels, const float* __restrict__ Wt, const float* __restrict__ bt,
    const float* __restrict__ Wtime, const float* __restrict__ Wedge,
    const __hip_bfloat16* __restrict__ kaddg, const __hip_bfloat16* __restrict__ vaddg,
    const float* __restrict__ g2, const float* __restrict__ b2,
    float* __restrict__ H2, ushort* __restrict__ hnb){
  __shared__ float dt_sh[KK];
  __shared__ int valid_sh[KK];
  __shared__ int nbr_sh[KK];
  __shared__ float red[2];
  __shared__ float temb[PRECOMP?1:KK][2*TFH];
  __shared__ float rl[PRECOMP?1:KK][RFE];
  __shared__ float kadds[PRECOMP?1:KK][HH];
  __shared__ float vadds[PRECOMP?1:KK][HH];
  const int n = blockIdx.x, j = threadIdx.x;
  if (j < KK){
    const float t = times[n*KK + j];
    valid_sh[j] = (t >= START_T) && (t < END_T);
    nbr_sh[j] = nbrs[n*KK + j];
    if (!PRECOMP) dt_sh[j] = tmaxb[n] - t;
  }
  __syncthreads();
  if (!PRECOMP){
    {
      const int p0 = j >> 5, f = j & 31;
      const float wtf = Wt[f], btf = bt[f];
      #pragma unroll
      for (int pass=0; pass<8; ++pass){
        const int p = p0 + pass*4;
        const float hh = fmaf(dt_sh[p], wtf, btf);
        temb[p][2*f]   = __sinf(hh)*T_NORM;
        temb[p][2*f+1] = __cosf(hh)*T_NORM;
        rl[p][f] = rels[((size_t)n*KK + p)*RFE + f];
      }
    }
    __syncthreads();
    float ak[KK], av[KK];
    #pragma unroll
    for (int p=0;p<KK;p++){ ak[p]=0.f; av[p]=0.f; }
    for (int f=0; f<2*TFH; f++){
      const float wk = Wtime[f*384 + j], wv = Wtime[f*384 + 2*HH + j];
      #pragma unroll
      for (int p=0;p<KK;p++){ const float t=temb[p][f]; ak[p]=fmaf(t,wk,ak[p]); av[p]=fmaf(t,wv,av[p]); }
    }
    for (int r=0; r<RFE; r++){
      const float wk = Wedge[r*384 + j], wv = Wedge[r*384 + 2*HH + j];
      #pragma unroll
      for (int p=0;p<KK;p++){ const float t=rl[p][r]; ak[p]=fmaf(t,wk,ak[p]); av[p]=fmaf(t,wv,av[p]); }
    }
    #pragma unroll
    for (int p=0;p<KK;p++){ kadds[p][j]=ak[p]; vadds[p][j]=av[p]; }
    __syncthreads();
  }
  const float qv = KQV[(size_t)n*384 + HH + j];
  float m = -3.0e38f, l = 0.f, acc = 0.f;
  for (int k=0;k<KK;k++){
    if (valid_sh[k]){
      const int nbr = nbr_sh[k];
      float kaddv, vaddv;
      if (PRECOMP){
        kaddv = __bfloat162float(kaddg[((size_t)n*KK+k)*HH + j]);
        vaddv = __bfloat162float(vaddg[((size_t)n*KK+k)*HH + j]);
      } else {
        kaddv = kadds[k][j]; vaddv = vadds[k][j];
      }
      const float kv = KQV[(size_t)nbr*384 + j] + kaddv;
      float p = qv * kv;
      p += __shfl_xor(p, 8, 16);
      p += __shfl_xor(p, 4, 16);
      p += __shfl_xor(p, 2, 16);
      p += __shfl_xor(p, 1, 16);
      const float s = p * ATTN_NORM;
      const float mn = fmaxf(m, s);
      const float sc = __expf(m - mn);
      const float e  = __expf(s - mn);
      const float vv = KQV[(size_t)nbr*384 + 2*HH + j] + vaddv;
      l   = fmaf(l, sc, e);
      acc = fmaf(acc, sc, e*vv);
      m = mn;
    }
  }
  const float o = (l > 0.f) ? (acc / l) : 0.f;
  const float h2v = o + XN[(size_t)n*HH + j];
  H2[(size_t)n*HH + j] = h2v;
  // LN epilogue -> hnb (bf16), consumed by FFN GEMM
  const float mn2 = blocksum128(h2v, red)*(1.f/HH);
  const float d = h2v - mn2;
  const float var = blocksum128(d*d, red)*(1.f/HH);
  const float hnv = d*rsqrtf(var + LN_EPS)*g2[j] + b2[j];
  hnb[(size_t)n*HH + j] = f2bf(hnv);
}

// ---------- per layer: FFN via 2 MFMA GEMMs ----------
#define LDA2 264   // 256+8 pad
__global__ __launch_bounds__(256) void k_ffn_mfma(const ushort* __restrict__ xnb, const ushort* __restrict__ hnb,
    const float* __restrict__ H2, const ushort* __restrict__ W1T, const float* __restrict__ bl1,
    const ushort* __restrict__ W2T, const float* __restrict__ bl2, float* __restrict__ HOUT){
  __shared__ ushort As[16*LDA2];
  __shared__ ushort Ms[16*LDA1];
  const int tid = threadIdx.x, n0 = blockIdx.x*16;
  {
    const int row = tid>>4, c8 = (tid&15)*8;
    *(uint4*)&As[row*LDA2 + c8]       = *(const uint4*)&xnb[(size_t)(n0+row)*HH + c8];
    *(uint4*)&As[row*LDA2 + 128 + c8] = *(const uint4*)&hnb[(size_t)(n0+row)*HH + c8];
  }
  __syncthreads();
  const int w = tid>>6, lane = tid&63;
  const int lr = lane&15, lk8 = (lane>>4)*8, rbase = (lane>>4)*4;
  // GEMM1: [16x256] @ W1T[128][256]
  {
    bf16x8 a[8];
    #pragma unroll
    for (int kk=0;kk<8;kk++) a[kk] = *(const bf16x8*)&As[lr*LDA2 + kk*32 + lk8];
    f32x4 acc[2];
    #pragma unroll
    for (int nt=0;nt<2;nt++) acc[nt] = (f32x4){0.f,0.f,0.f,0.f};
    #pragma unroll
    for (int nt=0;nt<2;nt++){
      const int n = w*2 + nt;
      #pragma unroll
      for (int kk=0;kk<8;kk++){
        bf16x8 b = *(const bf16x8*)&W1T[(n*16+lr)*256 + kk*32 + lk8];
        acc[nt] = __builtin_amdgcn_mfma_f32_16x16x32_bf16(a[kk], b, acc[nt],0,0,0);
      }
    }
    #pragma unroll
    for (int nt=0;nt<2;nt++){
      const int c = (w*2+nt)*16 + lr;
      const float bj = bl1[c];
      #pragma unroll
      for (int r=0;r<4;r++)
        Ms[(rbase+r)*LDA1 + c] = f2bf(fmaxf(acc[nt][r] + bj, 0.f));
    }
  }
  __syncthreads();
  // GEMM2: [16x128] @ W2T[128][128]
  {
    bf16x8 a[4];
    #pragma unroll
    for (int kk=0;kk<4;kk++) a[kk] = *(const bf16x8*)&Ms[lr*LDA1 + kk*32 + lk8];
    f32x4 acc[2];
    #pragma unroll
    for (int nt=0;nt<2;nt++) acc[nt] = (f32x4){0.f,0.f,0.f,0.f};
    #pragma unroll
    for (int nt=0;nt<2;nt++){
      const int n = w*2 + nt;
      #pragma unroll
      for (int kk=0;kk<4;kk++){
        bf16x8 b = *(const bf16x8*)&W2T[(n*16+lr)*HH + kk*32 + lk8];
        acc[nt] = __builtin_amdgcn_mfma_f32_16x16x32_bf16(a[kk], b, acc[nt],0,0,0);
      }
    }
    #pragma unroll
    for (int nt=0;nt<2;nt++){
      const int c = (w*2+nt)*16 + lr;
      const float bj = bl2[c];
      #pragma unroll
      for (int r=0;r<4;r++){
        const size_t node = n0 + rbase + r;
        HOUT[node*HH + c] = acc[nt][r] + bj + H2[node*HH + c];
      }
    }
  }
}

// ---------- out = h @ Wo + bo (MFMA) ----------
__global__ __launch_bounds__(256) void k_out_mfma(const float* __restrict__ Hin, const ushort* __restrict__ WoT,
                                                  const float* __restrict__ bo, float* __restrict__ OUT){
  __shared__ ushort As[16*LDA1];
  const int tid = threadIdx.x, n0 = blockIdx.x*16;
  #pragma unroll
  for (int p=0;p<2;++p){
    const int idx = tid + p*256;
    const int row = idx>>5, c4 = (idx&31)*4;
    const float4 v = *(const float4*)&Hin[(size_t)(n0+row)*HH + c4];
    *(ushort4*)&As[row*LDA1 + c4] = make_ushort4(f2bf(v.x), f2bf(v.y), f2bf(v.z), f2bf(v.w));
  }
  __syncthreads();
  const int w = tid>>6, lane = tid&63;
  const int lr = lane&15, lk8 = (lane>>4)*8, rbase = (lane>>4)*4;
  bf16x8 a[4];
  #pragma unroll
  for (int kk=0;kk<4;kk++) a[kk] = *(const bf16x8*)&As[lr*LDA1 + kk*32 + lk8];
  f32x4 acc = (f32x4){0.f,0.f,0.f,0.f};
  #pragma unroll
  for (int kk=0;kk<4;kk++){
    bf16x8 b = *(const bf16x8*)&WoT[(w*16+lr)*HH + kk*32 + lk8];
    acc = __builtin_amdgcn_mfma_f32_16x16x32_bf16(a[kk], b, acc,0,0,0);
  }
  const int c = w*16 + lr;
  const float bj = bo[c];
  #pragma unroll
  for (int r=0;r<4;r++)
    OUT[(size_t)(n0 + rbase + r)*OUTF + c] = acc[r] + bj;
}

extern "C" void kernel_launch(void* const* d_in, const int* in_sizes, int n_in,
                              void* d_out, int out_size, void* d_ws, size_t ws_size,
                              hipStream_t stream){
  const float* x         = (const float*)d_in[0];
  const int*   neighbors = (const int*)  d_in[1];
  const float* times     = (const float*)d_in[2];
  const float* rels      = (const float*)d_in[3];
  const float* Wp        = (const float*)d_in[4];
  const float* bp        = (const float*)d_in[5];
  const float* Wkqv      = (const float*)d_in[6];
  const float* Wt        = (const float*)d_in[7];
  const float* bt        = (const float*)d_in[8];
  const float* Wtime     = (const float*)d_in[9];
  const float* Wedge     = (const float*)d_in[10];
  const float* g1        = (const float*)d_in[11];
  const float* b1n       = (const float*)d_in[12];
  const float* g2        = (const float*)d_in[13];
  const float* b2n       = (const float*)d_in[14];
  const float* W1        = (const float*)d_in[15];
  const float* bl1       = (const float*)d_in[16];
  const float* W2        = (const float*)d_in[17];
  const float* bl2       = (const float*)d_in[18];
  const float* Wo        = (const float*)d_in[19];
  const float* bo        = (const float*)d_in[20];
  float* out = (float*)d_out;

  char* ws = (char*)d_ws;
  size_t off = 0;
  auto carve = [&](size_t bytes)->char*{
    char* p = ws + off; off = (off + bytes + 255) & ~(size_t)255; return p;
  };
  float* hA    = (float*)carve((size_t)NN*HH*4);
  float* hB    = (float*)carve((size_t)NN*HH*4);
  float* xn    = (float*)carve((size_t)NN*HH*4);
  float* h2    = (float*)carve((size_t)NN*HH*4);
  float* tqq   = (float*)carve((size_t)NN*HH*4);
  float* kqv   = (float*)carve((size_t)NN*384*4);
  float* tmaxb = (float*)carve((size_t)NN*4);
  ushort* xnb  = (ushort*)carve((size_t)NN*HH*2);
  ushort* hnb  = (ushort*)carve((size_t)NN*HH*2);
  ushort* WcTg = (ushort*)carve((size_t)256*96*2);
  ushort* WpT  = (ushort*)carve((size_t)16384*2);
  ushort* WkqvT= (ushort*)carve((size_t)49152*2);
  ushort* W1T  = (ushort*)carve((size_t)32768*2);
  ushort* W2T  = (ushort*)carve((size_t)16384*2);
  ushort* WoT  = (ushort*)carve((size_t)8192*2);
  __hip_bfloat16* kaddg = (__hip_bfloat16*)carve((size_t)NN*KK*HH*2);
  __hip_bfloat16* vaddg = (__hip_bfloat16*)carve((size_t)NN*KK*HH*2);
  const bool precomp = (ws_size >= off);

  k_prep_wT<<<480, 256, 0, stream>>>(Wp, Wkqv, W1, W2, Wo, WpT, WkqvT, W1T, W2T, WoT);
  k_proj_mfma<<<NN/16, 256, 0, stream>>>(x, WpT, bp, hA);
  k_prep_node<<<NN, 128, 0, stream>>>(times, Wt, bt, Wtime, tqq, tmaxb);
  if (precomp){
    k_prep_w<<<96, 256, 0, stream>>>(Wtime, Wedge, WcTg);
    k_prep_kv_mfma<<<NN/2, 256, 0, stream>>>(times, rels, tmaxb, Wt, bt, WcTg, kaddg, vaddg);
  }

  float* cur = hA; float* nxt = hB;
  for (int layer=0; layer<2; ++layer){
    k_ln_kqv_mfma<<<NN/16, 256, 0, stream>>>(cur, WkqvT, g1, b1n, tqq, xn, xnb, kqv);
    if (precomp)
      k_attn<true><<<NN, 128, 0, stream>>>(kqv, xn, tmaxb, times, neighbors, rels,
                                           Wt, bt, Wtime, Wedge, kaddg, vaddg, g2, b2n, h2, hnb);
    else
      k_attn<false><<<NN, 128, 0, stream>>>(kqv, xn, tmaxb, times, neighbors, rels,
                                            Wt, bt, Wtime, Wedge, kaddg, vaddg, g2, b2n, h2, hnb);
    k_ffn_mfma<<<NN/16, 256, 0, stream>>>(xnb, hnb, h2, W1T, bl1, W2T, bl2, nxt);
    float* t = cur; cur = nxt; nxt = t;
  }
  k_out_mfma<<<NN/16, 256, 0, stream>>>(cur, WoT, bo, out);
}